// Round 6
// baseline (5620.922 us; speedup 1.0000x reference)
//
#include <hip/hip_runtime.h>

// ---------------------------------------------------------------------------
// GCNConvNet: 2x GIN conv (shared aggregation) + dense head. fp32 I/O,
// bf16 MFMA internally (harness grants bf16 tolerance).
// Round 6: latency-tolerant GEMM K-loop (r5: MfmaUtil 19%, latency-bound):
//   (a) 3-stage LDS pipeline, prefetch distance 2, manual
//       "s_waitcnt vmcnt(4); s_barrier" instead of __syncthreads' vmcnt(0)
//       drain -> every global_load_lds gets 2 compute phases to land.
//   (b) XCD-slice swizzle (id&7 -> nt slice) where nt_total%8==0 -> B tiles
//       L2-resident per XCD (~1-2MB), A-tile reuse across the slice.
// CSR-gather aggregation unchanged.
// ---------------------------------------------------------------------------

#define NN 60000
#define NE 960000
#define C_IN 128
#define HID 512
#define DCAT 1024
#define DFC 2048
#define DL1 4096
#define OUTC 64

typedef __bf16 bf16x8 __attribute__((ext_vector_type(8)));
typedef float floatx4 __attribute__((ext_vector_type(4)));

__device__ __forceinline__ unsigned short f2b(float f) {
  unsigned int u = __float_as_uint(f);
  unsigned int r = (u + 0x7fffu + ((u >> 16) & 1u)) >> 16;  // RNE, finite inputs
  return (unsigned short)r;
}

// async global->LDS, 16B per lane; LDS dest = wave-uniform base + lane*16
#define GLOAD_LDS16(g, l)                                                     \
  __builtin_amdgcn_global_load_lds(                                           \
      (__attribute__((address_space(1))) void*)(g),                           \
      (__attribute__((address_space(3))) void*)(l), 16, 0, 0)

// ---------------------------------------------------------------------------
__global__ void k_bnparams(const float* __restrict__ g,
                           const float* __restrict__ be,
                           const float* __restrict__ mn,
                           const float* __restrict__ vr,
                           const float* __restrict__ b1,
                           float* __restrict__ scale, float* __restrict__ shift) {
  int i = blockIdx.x * 256 + threadIdx.x;
  if (i < HID) {
    float s = g[i] * rsqrtf(vr[i] + 1e-5f);
    scale[i] = s;
    shift[i] = (b1[i] - mn[i]) * s + be[i];
  }
}

// fp32 [K,N] -> bf16 [N,K] transpose+downcast, 32x32 tiles
__global__ void k_transpose(const float* __restrict__ in,
                            unsigned short* __restrict__ out, int K, int N) {
  __shared__ float t[32][33];
  int n0 = blockIdx.x * 32, k0 = blockIdx.y * 32;
  int tx = threadIdx.x & 31, ty = threadIdx.x >> 5;  // 32 x 8
#pragma unroll
  for (int i = 0; i < 32; i += 8)
    t[ty + i][tx] = in[(size_t)(k0 + ty + i) * N + n0 + tx];
  __syncthreads();
#pragma unroll
  for (int i = 0; i < 32; i += 8)
    out[(size_t)(n0 + ty + i) * K + k0 + tx] = f2b(t[tx][ty + i]);
}

// ---------------------------------------------------------------------------
// CSR build: deg -> exclusive scan (3 kernels) -> bucket src ids -> gather.
__global__ void k_deg(const int* __restrict__ dst, int* __restrict__ deg) {
  int e = blockIdx.x * 256 + threadIdx.x;
  if (e < NE) atomicAdd(&deg[dst[e]], 1);
}

__global__ void k_scan1(const int* __restrict__ deg, int* __restrict__ offs,
                        int* __restrict__ bsum) {
  __shared__ int t[256];
  int i = blockIdx.x * 256 + threadIdx.x;
  int v = (i < NN) ? deg[i] : 0;
  t[threadIdx.x] = v;
  __syncthreads();
#pragma unroll
  for (int d = 1; d < 256; d <<= 1) {
    int add = (threadIdx.x >= d) ? t[threadIdx.x - d] : 0;
    __syncthreads();
    t[threadIdx.x] += add;
    __syncthreads();
  }
  if (i < NN) offs[i] = t[threadIdx.x] - v;
  if (threadIdx.x == 255) bsum[blockIdx.x] = t[255];
}

__global__ void k_scan2(int* __restrict__ bsum, int nb) {
  __shared__ int t[256];
  int v = (threadIdx.x < nb) ? bsum[threadIdx.x] : 0;
  t[threadIdx.x] = v;
  __syncthreads();
#pragma unroll
  for (int d = 1; d < 256; d <<= 1) {
    int add = (threadIdx.x >= d) ? t[threadIdx.x - d] : 0;
    __syncthreads();
    t[threadIdx.x] += add;
    __syncthreads();
  }
  if (threadIdx.x < nb) bsum[threadIdx.x] = t[threadIdx.x] - v;
}

__global__ void k_scan3(int* __restrict__ offs, const int* __restrict__ bsum,
                        int* __restrict__ cursor) {
  int i = blockIdx.x * 256 + threadIdx.x;
  if (i < NN) {
    int o = offs[i] + bsum[blockIdx.x];
    offs[i] = o;
    cursor[i] = o;
  }
  if (i == 0) offs[NN] = NE;
}

__global__ void k_bucket(const int* __restrict__ src, const int* __restrict__ dst,
                         int* __restrict__ cursor, int* __restrict__ esrc) {
  int e = blockIdx.x * 256 + threadIdx.x;
  if (e < NE) {
    int slot = atomicAdd(&cursor[dst[e]], 1);
    esrc[slot] = src[e];
  }
}

// one wave per node: h0[node] = bf16(x[node] + sum_j x[esrc[j]]), f32 accum
__global__ void k_agg(const float2* __restrict__ x2, const int* __restrict__ offs,
                      const int* __restrict__ esrc, unsigned int* __restrict__ h0u) {
  int node = blockIdx.x * 4 + (threadIdx.x >> 6);
  if (node >= NN) return;
  int lane = threadIdx.x & 63;
  int beg = offs[node], end = offs[node + 1];
  float2 acc = x2[(size_t)node * 64 + lane];
  for (int j = beg; j < end; j++) {
    int s = esrc[j];  // wave-uniform -> broadcast load
    float2 v = x2[(size_t)s * 64 + lane];
    acc.x += v.x;
    acc.y += v.y;
  }
  h0u[(size_t)node * 64 + lane] =
      (unsigned)f2b(acc.x) | ((unsigned)f2b(acc.y) << 16);
}

// ---------------------------------------------------------------------------
// GEMM: C[M,N] = A[M,K](row-stride lda) @ Bt[N,K]^T, bf16 in, f32 accum.
// 128x128 tile, BK=32, 4 waves (2x2), each wave 64x64 via 4x4 MFMA 16x16x32.
// 3-stage LDS pipeline, prefetch distance 2. Barrier = manual
// "s_waitcnt vmcnt(4); s_barrier": the 4 newest loads (tile t+1, issued last
// iter) may stay in flight; tile t's loads (issued 2 iters ago) are drained.
// Swizzle: XCD slice (id&7 -> nt range) when nt_total%8==0, else GM-groups.
// EPI: 0=bias, 1=bias+relu, 2=bn+relu, 3=bias+leaky, 4=bias+sigmoid->fp32
template <int EPI>
__global__ __launch_bounds__(256) void k_gemm(
    const unsigned short* __restrict__ A, const unsigned short* __restrict__ Bt,
    unsigned short* __restrict__ C, const float* __restrict__ bias,
    const float* __restrict__ scale, const float* __restrict__ shift,
    int M, int N, int K, int lda, int ldc) {
  __shared__ __align__(16) unsigned short lsA[3][4][128][8];
  __shared__ __align__(16) unsigned short lsB[3][4][128][8];

  const int tid = threadIdx.x;
  const int w = tid >> 6;
  const int lane = tid & 63;
  const int quad = lane >> 4;
  const int r16 = lane & 15;
  const int wm = w >> 1, wn = w & 1;

  // ---- block swizzle ----
  const int mt_total = (M + 127) >> 7, nt_total = (N + 127) >> 7;
  int mt, nt;
  if ((nt_total & 7) == 0) {
    // XCD-slice: XCD x owns nts [x*ntpx, (x+1)*ntpx); consecutive per-XCD
    // blocks share mt -> A-tile L2 reuse; B slice (<=2MB) stays L2-resident.
    const int ntpx = nt_total >> 3;
    const int x = blockIdx.x & 7;
    const int s = blockIdx.x >> 3;
    nt = x * ntpx + (s % ntpx);
    mt = s / ntpx;
  } else {
    const int GM = 8;
    const int full = (mt_total / GM) * GM;
    const int boundary = full * nt_total;
    int id = blockIdx.x;
    if (id < boundary) {
      int per_group = GM * nt_total;
      int g = id / per_group, r = id % per_group;
      mt = g * GM + r % GM;
      nt = r / GM;
    } else {
      int r = id - boundary, gm = mt_total - full;
      mt = full + r % gm;
      nt = r / gm;
    }
  }
  const int m0 = mt << 7;
  const int n0 = nt << 7;

  const int ra0 = min(m0 + lane, M - 1);
  const int ra1 = min(m0 + 64 + lane, M - 1);
  const int rb0 = min(n0 + lane, N - 1);
  const int rb1 = min(n0 + 64 + lane, N - 1);
  const unsigned short* pA0 = A + (size_t)ra0 * lda + w * 8;
  const unsigned short* pA1 = A + (size_t)ra1 * lda + w * 8;
  const unsigned short* pB0 = Bt + (size_t)rb0 * K + w * 8;
  const unsigned short* pB1 = Bt + (size_t)rb1 * K + w * 8;

  floatx4 acc[4][4];
#pragma unroll
  for (int i = 0; i < 4; i++)
#pragma unroll
    for (int j = 0; j < 4; j++) acc[i][j] = (floatx4){0.f, 0.f, 0.f, 0.f};

  const int niter = K >> 5;

#define ISSUE_TILE(st)                                                        \
  do {                                                                        \
    GLOAD_LDS16(pA0, &lsA[st][w][0][0]);                                      \
    GLOAD_LDS16(pA1, &lsA[st][w][64][0]);                                     \
    GLOAD_LDS16(pB0, &lsB[st][w][0][0]);                                      \
    GLOAD_LDS16(pB1, &lsB[st][w][64][0]);                                     \
    pA0 += 32; pA1 += 32; pB0 += 32; pB1 += 32;                               \
  } while (0)

  ISSUE_TILE(0);
  if (niter > 1) ISSUE_TILE(1);

  int sk = 0;
  for (int t = 0; t < niter; t++) {
    // need stage sk (tile t, loads issued 2 iters ago) complete; allow the
    // 4 newest (tile t+1) to remain in flight.
    if (t + 1 < niter) {
      asm volatile("s_waitcnt vmcnt(4)\n\ts_barrier" ::: "memory");
    } else {
      asm volatile("s_waitcnt vmcnt(0)\n\ts_barrier" ::: "memory");
    }
    if (t + 2 < niter) {
      int s2 = sk + 2;
      if (s2 >= 3) s2 -= 3;
      ISSUE_TILE(s2);
    }

    bf16x8 af[4], bfr[4];
#pragma unroll
    for (int i = 0; i < 4; i++)
      af[i] = *(const bf16x8*)&lsA[sk][quad][wm * 64 + i * 16 + r16][0];
#pragma unroll
    for (int j = 0; j < 4; j++)
      bfr[j] = *(const bf16x8*)&lsB[sk][quad][wn * 64 + j * 16 + r16][0];
#pragma unroll
    for (int i = 0; i < 4; i++)
#pragma unroll
      for (int j = 0; j < 4; j++)
        acc[i][j] = __builtin_amdgcn_mfma_f32_16x16x32_bf16(af[i], bfr[j],
                                                            acc[i][j], 0, 0, 0);
    sk = (sk + 1 == 3) ? 0 : sk + 1;
  }
#undef ISSUE_TILE

  // epilogue: C/D layout col=lane&15, row=quad*4+reg  [m89-verified]
#pragma unroll
  for (int j = 0; j < 4; j++) {
    int gn = n0 + wn * 64 + j * 16 + r16;
    int cn = gn < N ? gn : 0;
    float p0, p1 = 0.f;
    if constexpr (EPI == 2) {
      p0 = scale[cn];
      p1 = shift[cn];
    } else {
      p0 = bias[cn];
    }
#pragma unroll
    for (int i = 0; i < 4; i++) {
#pragma unroll
      for (int t = 0; t < 4; t++) {
        int gm = m0 + wm * 64 + i * 16 + quad * 4 + t;
        if (gm < M && gn < N) {
          float v = acc[i][j][t];
          if constexpr (EPI == 0) {
            v += p0;
            C[(size_t)gm * ldc + gn] = f2b(v);
          } else if constexpr (EPI == 1) {
            v += p0; v = v > 0.f ? v : 0.f;
            C[(size_t)gm * ldc + gn] = f2b(v);
          } else if constexpr (EPI == 2) {
            v = v * p0 + p1; v = v > 0.f ? v : 0.f;
            C[(size_t)gm * ldc + gn] = f2b(v);
          } else if constexpr (EPI == 3) {
            v += p0; v = v > 0.f ? v : 0.01f * v;
            C[(size_t)gm * ldc + gn] = f2b(v);
          } else {  // sigmoid -> fp32 network output
            v += p0;
            v = 1.f / (1.f + __expf(-v));
            ((float*)C)[(size_t)gm * ldc + gn] = v;
          }
        }
      }
    }
  }
}

// ---------------------------------------------------------------------------
extern "C" void kernel_launch(void* const* d_in, const int* in_sizes, int n_in,
                              void* d_out, int out_size, void* d_ws,
                              size_t ws_size, hipStream_t stream) {
  typedef const float* cf;
  cf x = (cf)d_in[0];
  const int* ei = (const int*)d_in[1];
  const int* srcI = ei;
  const int* dstI = ei + NE;
  cf w1a = (cf)d_in[2],  b1a = (cf)d_in[3];
  cf ga = (cf)d_in[4],   bea = (cf)d_in[5];
  cf mna = (cf)d_in[6],  vra = (cf)d_in[7];
  cf w2a = (cf)d_in[8],  b2a = (cf)d_in[9];
  cf w1b = (cf)d_in[10], b1b = (cf)d_in[11];
  cf gb = (cf)d_in[12],  beb = (cf)d_in[13];
  cf mnb = (cf)d_in[14], vrb = (cf)d_in[15];
  cf w2b = (cf)d_in[16], b2b = (cf)d_in[17];
  cf fc_w = (cf)d_in[18], fc_b = (cf)d_in[19];
  cf l1_w = (cf)d_in[20], l1_b = (cf)d_in[21];
  cf l2_w = (cf)d_in[22], l2_b = (cf)d_in[23];
  cf ow = (cf)d_in[24],   ob = (cf)d_in[25];
  float* outf = (float*)d_out;

  // ---- workspace carve-up ----------------------------------------------------
  char* ws = (char*)d_ws;
  size_t off = 0;
  auto carve = [&](size_t bytes) {
    void* p = ws + off;
    off += (bytes + 255) & ~(size_t)255;
    return p;
  };
  // persistent (~53 MB): transposed weights + h0 + folded BN params
  unsigned short* wt1ab = (unsigned short*)carve((size_t)DCAT * C_IN * 2);
  unsigned short* wt2a = (unsigned short*)carve((size_t)HID * HID * 2);
  unsigned short* wt2b = (unsigned short*)carve((size_t)HID * HID * 2);
  unsigned short* wtfc = (unsigned short*)carve((size_t)DFC * DCAT * 2);
  unsigned short* wtl1 = (unsigned short*)carve((size_t)DL1 * DFC * 2);
  unsigned short* wtl2 = (unsigned short*)carve((size_t)DFC * DL1 * 2);
  unsigned short* wtout = (unsigned short*)carve((size_t)OUTC * DFC * 2);
  float* scale_ab = (float*)carve(DCAT * 4);
  float* shift_ab = (float*)carve(DCAT * 4);
  unsigned short* h0 = (unsigned short*)carve((size_t)NN * C_IN * 2);

  // phase-1-only CSR arrays, OVERLAID with phase-2 activation buffers
  size_t off_overlay = off;
  int* deg = (int*)carve((size_t)NN * 4);
  int* offs = (int*)carve((size_t)(NN + 1) * 4);
  int* cursor = (int*)carve((size_t)NN * 4);
  int* bsum = (int*)carve(256 * 4);
  int* esrc = (int*)carve((size_t)NE * 4);

  // phase-2 activations from the overlay region start
  off = off_overlay;
  size_t rem = (ws_size > off + 4096) ? (ws_size - off - 4096) : 0;
  int mchunk = (int)(rem / ((DFC + DL1) * 2));
  if (mchunk > 15104) mchunk = 15104;
  mchunk &= ~127;
  if (mchunk < 128) mchunk = 128;
  unsigned short* bufA = (unsigned short*)carve((size_t)mchunk * DFC * 2);
  unsigned short* bufB = (unsigned short*)carve((size_t)mchunk * DL1 * 2);
  (void)in_sizes; (void)n_in; (void)out_size;

  // ---- phase 0: params + weight transposes ----------------------------------
  k_bnparams<<<2, 256, 0, stream>>>(ga, bea, mna, vra, b1a, scale_ab, shift_ab);
  k_bnparams<<<2, 256, 0, stream>>>(gb, beb, mnb, vrb, b1b, scale_ab + HID,
                                    shift_ab + HID);
  k_transpose<<<dim3(HID / 32, C_IN / 32), 256, 0, stream>>>(w1a, wt1ab, C_IN, HID);
  k_transpose<<<dim3(HID / 32, C_IN / 32), 256, 0, stream>>>(
      w1b, wt1ab + (size_t)HID * C_IN, C_IN, HID);
  k_transpose<<<dim3(HID / 32, HID / 32), 256, 0, stream>>>(w2a, wt2a, HID, HID);
  k_transpose<<<dim3(HID / 32, HID / 32), 256, 0, stream>>>(w2b, wt2b, HID, HID);
  k_transpose<<<dim3(DFC / 32, DCAT / 32), 256, 0, stream>>>(fc_w, wtfc, DCAT, DFC);
  k_transpose<<<dim3(DL1 / 32, DFC / 32), 256, 0, stream>>>(l1_w, wtl1, DFC, DL1);
  k_transpose<<<dim3(DFC / 32, DL1 / 32), 256, 0, stream>>>(l2_w, wtl2, DL1, DFC);
  k_transpose<<<dim3(OUTC / 32, DFC / 32), 256, 0, stream>>>(ow, wtout, DFC, OUTC);

  // ---- phase 1: CSR build + gather aggregation -------------------------------
  const int NB_NODE = (NN + 255) / 256;
  hipMemsetAsync(deg, 0, (size_t)NN * 4, stream);
  k_deg<<<(NE + 255) / 256, 256, 0, stream>>>(dstI, deg);
  k_scan1<<<NB_NODE, 256, 0, stream>>>(deg, offs, bsum);
  k_scan2<<<1, 256, 0, stream>>>(bsum, NB_NODE);
  k_scan3<<<NB_NODE, 256, 0, stream>>>(offs, bsum, cursor);
  k_bucket<<<(NE + 255) / 256, 256, 0, stream>>>(srcI, dstI, cursor, esrc);
  k_agg<<<(NN + 3) / 4, 256, 0, stream>>>((const float2*)x, offs, esrc,
                                          (unsigned int*)h0);

  // ---- phase 2: GEMM chain, M in adaptive chunks -----------------------------
  auto gemm = [&](int epi, const unsigned short* A, const unsigned short* Bt,
                  unsigned short* Cp, cf bias, const float* sc, const float* sh,
                  int M, int N, int K, int lda, int ldc) {
    dim3 g(((M + 127) / 128) * ((N + 127) / 128));
    switch (epi) {
      case 0: k_gemm<0><<<g, 256, 0, stream>>>(A, Bt, Cp, bias, sc, sh, M, N, K, lda, ldc); break;
      case 1: k_gemm<1><<<g, 256, 0, stream>>>(A, Bt, Cp, bias, sc, sh, M, N, K, lda, ldc); break;
      case 2: k_gemm<2><<<g, 256, 0, stream>>>(A, Bt, Cp, bias, sc, sh, M, N, K, lda, ldc); break;
      case 3: k_gemm<3><<<g, 256, 0, stream>>>(A, Bt, Cp, bias, sc, sh, M, N, K, lda, ldc); break;
      default: k_gemm<4><<<g, 256, 0, stream>>>(A, Bt, Cp, bias, sc, sh, M, N, K, lda, ldc); break;
    }
  };

  for (int m0 = 0; m0 < NN; m0 += mchunk) {
    const int M = (NN - m0 < mchunk) ? (NN - m0) : mchunk;
    const unsigned short* h0c = h0 + (size_t)m0 * C_IN;
    unsigned short* outc = (unsigned short*)(outf + (size_t)m0 * OUTC);
    // fused branch-1: t1 = BN+ReLU(h0 @ [w1a|w1b])  (M x 1024), bufA ld=1024
    gemm(2, h0c, wt1ab, bufA, nullptr, scale_ab, shift_ab, M, DCAT, C_IN, C_IN, DCAT);
    // branch-2a/b: xcat halves (bufB, ld=1024)
    gemm(1, bufA, wt2a, bufB, b2a, nullptr, nullptr, M, HID, HID, DCAT, DCAT);
    gemm(1, bufA + HID, wt2b, bufB + HID, b2b, nullptr, nullptr, M, HID, HID, DCAT, DCAT);
    // head: xcat(bufB,1024) -> hfc(bufA,2048) -> hl1(bufB,4096) -> hl2(bufA,2048) -> out(fp32)
    gemm(3, bufB, wtfc, bufA, fc_b, nullptr, nullptr, M, DFC, DCAT, DCAT, DFC);
    gemm(0, bufA, wtl1, bufB, l1_b, nullptr, nullptr, M, DL1, DFC, DFC, DL1);
    gemm(0, bufB, wtl2, bufA, l2_b, nullptr, nullptr, M, DFC, DL1, DL1, DFC);
    gemm(4, bufA, wtout, outc, ob, nullptr, nullptr, M, OUTC, DFC, DFC, OUTC);
  }
}

// Round 7
// 5121.461 us; speedup vs baseline: 1.0975x; 1.0975x over previous
//
#include <hip/hip_runtime.h>

// ---------------------------------------------------------------------------
// GCNConvNet: 2x GIN conv (shared aggregation) + dense head. fp32 I/O,
// bf16 MFMA internally (harness grants bf16 tolerance).
// Round 7: bigger wave tiles. r4-r6 all pinned at MfmaUtil ~19.5% regardless
// of pipelining -> binder is per-wave fixed overhead (8 ds_read_b128 + 6
// scattered glds per 16 MFMAs). New geometry: block 128x256, 4 waves, each
// wave 128x64 (acc 128 VGPRs): 12 ds_reads + 6 glds per 32 MFMAs = 2x MACs
// per unit of LDS/VMEM overhead. 3-stage LDS pipeline, vmcnt(6) partial
// drain, XCD-slice/GM swizzle kept.
// ---------------------------------------------------------------------------

#define NN 60000
#define NE 960000
#define C_IN 128
#define HID 512
#define DCAT 1024
#define DFC 2048
#define DL1 4096
#define OUTC 64

typedef __bf16 bf16x8 __attribute__((ext_vector_type(8)));
typedef float floatx4 __attribute__((ext_vector_type(4)));

__device__ __forceinline__ unsigned short f2b(float f) {
  unsigned int u = __float_as_uint(f);
  unsigned int r = (u + 0x7fffu + ((u >> 16) & 1u)) >> 16;  // RNE, finite inputs
  return (unsigned short)r;
}

// async global->LDS, 16B per lane; LDS dest = wave-uniform base + lane*16
#define GLOAD_LDS16(g, l)                                                     \
  __builtin_amdgcn_global_load_lds(                                           \
      (__attribute__((address_space(1))) void*)(g),                           \
      (__attribute__((address_space(3))) void*)(l), 16, 0, 0)

// ---------------------------------------------------------------------------
__global__ void k_bnparams(const float* __restrict__ g,
                           const float* __restrict__ be,
                           const float* __restrict__ mn,
                           const float* __restrict__ vr,
                           const float* __restrict__ b1,
                           float* __restrict__ scale, float* __restrict__ shift) {
  int i = blockIdx.x * 256 + threadIdx.x;
  if (i < HID) {
    float s = g[i] * rsqrtf(vr[i] + 1e-5f);
    scale[i] = s;
    shift[i] = (b1[i] - mn[i]) * s + be[i];
  }
}

// fp32 [K,N] -> bf16 [N,K] transpose+downcast, 32x32 tiles
__global__ void k_transpose(const float* __restrict__ in,
                            unsigned short* __restrict__ out, int K, int N) {
  __shared__ float t[32][33];
  int n0 = blockIdx.x * 32, k0 = blockIdx.y * 32;
  int tx = threadIdx.x & 31, ty = threadIdx.x >> 5;  // 32 x 8
#pragma unroll
  for (int i = 0; i < 32; i += 8)
    t[ty + i][tx] = in[(size_t)(k0 + ty + i) * N + n0 + tx];
  __syncthreads();
#pragma unroll
  for (int i = 0; i < 32; i += 8)
    out[(size_t)(n0 + ty + i) * K + k0 + tx] = f2b(t[tx][ty + i]);
}

// ---------------------------------------------------------------------------
// CSR build: deg -> exclusive scan (3 kernels) -> bucket src ids -> gather.
__global__ void k_deg(const int* __restrict__ dst, int* __restrict__ deg) {
  int e = blockIdx.x * 256 + threadIdx.x;
  if (e < NE) atomicAdd(&deg[dst[e]], 1);
}

__global__ void k_scan1(const int* __restrict__ deg, int* __restrict__ offs,
                        int* __restrict__ bsum) {
  __shared__ int t[256];
  int i = blockIdx.x * 256 + threadIdx.x;
  int v = (i < NN) ? deg[i] : 0;
  t[threadIdx.x] = v;
  __syncthreads();
#pragma unroll
  for (int d = 1; d < 256; d <<= 1) {
    int add = (threadIdx.x >= d) ? t[threadIdx.x - d] : 0;
    __syncthreads();
    t[threadIdx.x] += add;
    __syncthreads();
  }
  if (i < NN) offs[i] = t[threadIdx.x] - v;
  if (threadIdx.x == 255) bsum[blockIdx.x] = t[255];
}

__global__ void k_scan2(int* __restrict__ bsum, int nb) {
  __shared__ int t[256];
  int v = (threadIdx.x < nb) ? bsum[threadIdx.x] : 0;
  t[threadIdx.x] = v;
  __syncthreads();
#pragma unroll
  for (int d = 1; d < 256; d <<= 1) {
    int add = (threadIdx.x >= d) ? t[threadIdx.x - d] : 0;
    __syncthreads();
    t[threadIdx.x] += add;
    __syncthreads();
  }
  if (threadIdx.x < nb) bsum[threadIdx.x] = t[threadIdx.x] - v;
}

__global__ void k_scan3(int* __restrict__ offs, const int* __restrict__ bsum,
                        int* __restrict__ cursor) {
  int i = blockIdx.x * 256 + threadIdx.x;
  if (i < NN) {
    int o = offs[i] + bsum[blockIdx.x];
    offs[i] = o;
    cursor[i] = o;
  }
  if (i == 0) offs[NN] = NE;
}

__global__ void k_bucket(const int* __restrict__ src, const int* __restrict__ dst,
                         int* __restrict__ cursor, int* __restrict__ esrc) {
  int e = blockIdx.x * 256 + threadIdx.x;
  if (e < NE) {
    int slot = atomicAdd(&cursor[dst[e]], 1);
    esrc[slot] = src[e];
  }
}

// one wave per node: h0[node] = bf16(x[node] + sum_j x[esrc[j]]), f32 accum
__global__ void k_agg(const float2* __restrict__ x2, const int* __restrict__ offs,
                      const int* __restrict__ esrc, unsigned int* __restrict__ h0u) {
  int node = blockIdx.x * 4 + (threadIdx.x >> 6);
  if (node >= NN) return;
  int lane = threadIdx.x & 63;
  int beg = offs[node], end = offs[node + 1];
  float2 acc = x2[(size_t)node * 64 + lane];
  for (int j = beg; j < end; j++) {
    int s = esrc[j];  // wave-uniform -> broadcast load
    float2 v = x2[(size_t)s * 64 + lane];
    acc.x += v.x;
    acc.y += v.y;
  }
  h0u[(size_t)node * 64 + lane] =
      (unsigned)f2b(acc.x) | ((unsigned)f2b(acc.y) << 16);
}

// ---------------------------------------------------------------------------
// GEMM: C[M,N] = A[M,K](row-stride lda) @ Bt[N,K]^T, bf16 in, f32 accum.
// Block tile 128x256, BK=32, 4 waves; wave w computes ALL 128 rows x 64 cols
// [w*64, w*64+64) via 8x4 grid of 16x16x32 MFMAs (acc 128 f32/lane).
// Per wave per iter: 12 ds_read_b128 + 6 global_load_lds for 32 MFMAs.
// 3-stage LDS pipeline, prefetch distance 2, "s_waitcnt vmcnt(6); s_barrier".
// EPI: 0=bias, 1=bias+relu, 2=bn+relu, 3=bias+leaky, 4=bias+sigmoid->fp32
template <int EPI>
__global__ __launch_bounds__(256, 2) void k_gemm(
    const unsigned short* __restrict__ A, const unsigned short* __restrict__ Bt,
    unsigned short* __restrict__ C, const float* __restrict__ bias,
    const float* __restrict__ scale, const float* __restrict__ shift,
    int M, int N, int K, int lda, int ldc) {
  __shared__ __align__(16) unsigned short lsA[3][4][128][8];  // 24 KB
  __shared__ __align__(16) unsigned short lsB[3][4][256][8];  // 48 KB

  const int tid = threadIdx.x;
  const int w = tid >> 6;
  const int lane = tid & 63;
  const int quad = lane >> 4;
  const int r16 = lane & 15;

  // ---- block swizzle (M tiles of 128, N tiles of 256) ----
  const int mt_total = (M + 127) >> 7, nt_total = (N + 255) >> 8;
  int mt, nt;
  if ((nt_total & 7) == 0) {
    // XCD-slice: XCD x owns a contiguous nt range; B slice stays L2-resident.
    const int ntpx = nt_total >> 3;
    const int x = blockIdx.x & 7;
    const int s = blockIdx.x >> 3;
    nt = x * ntpx + (s % ntpx);
    mt = s / ntpx;
  } else {
    const int GM = 8;
    const int full = (mt_total / GM) * GM;
    const int boundary = full * nt_total;
    int id = blockIdx.x;
    if (id < boundary) {
      int per_group = GM * nt_total;
      int g = id / per_group, r = id % per_group;
      mt = g * GM + r % GM;
      nt = r / GM;
    } else {
      int r = id - boundary, gm = mt_total - full;
      mt = full + r % gm;
      nt = r / gm;
    }
  }
  const int m0 = mt << 7;
  const int n0 = nt << 8;

  // staging rows (clamped for edge tiles; stores masked below)
  const int ra0 = min(m0 + lane, M - 1);
  const int ra1 = min(m0 + 64 + lane, M - 1);
  const unsigned short* pA0 = A + (size_t)ra0 * lda + w * 8;
  const unsigned short* pA1 = A + (size_t)ra1 * lda + w * 8;
  const unsigned short* pB[4];
#pragma unroll
  for (int seg = 0; seg < 4; seg++) {
    int rb = min(n0 + seg * 64 + lane, N - 1);
    pB[seg] = Bt + (size_t)rb * K + w * 8;
  }

  floatx4 acc[8][4];
#pragma unroll
  for (int i = 0; i < 8; i++)
#pragma unroll
    for (int j = 0; j < 4; j++) acc[i][j] = (floatx4){0.f, 0.f, 0.f, 0.f};

  const int niter = K >> 5;

#define ISSUE_TILE(st)                                                        \
  do {                                                                        \
    GLOAD_LDS16(pA0, &lsA[st][w][0][0]);                                      \
    GLOAD_LDS16(pA1, &lsA[st][w][64][0]);                                     \
    GLOAD_LDS16(pB[0], &lsB[st][w][0][0]);                                    \
    GLOAD_LDS16(pB[1], &lsB[st][w][64][0]);                                   \
    GLOAD_LDS16(pB[2], &lsB[st][w][128][0]);                                  \
    GLOAD_LDS16(pB[3], &lsB[st][w][192][0]);                                  \
    pA0 += 32; pA1 += 32;                                                     \
    pB[0] += 32; pB[1] += 32; pB[2] += 32; pB[3] += 32;                       \
  } while (0)

  ISSUE_TILE(0);
  if (niter > 1) ISSUE_TILE(1);

  int sk = 0;
  for (int t = 0; t < niter; t++) {
    // tile t's 6 loads (issued 2 iters ago) must be done; tile t+1's 6
    // newest may remain in flight. Each wave drains its own before barrier.
    if (t + 1 < niter) {
      asm volatile("s_waitcnt vmcnt(6)\n\ts_barrier" ::: "memory");
    } else {
      asm volatile("s_waitcnt vmcnt(0)\n\ts_barrier" ::: "memory");
    }
    if (t + 2 < niter) {
      int s2 = sk + 2;
      if (s2 >= 3) s2 -= 3;
      ISSUE_TILE(s2);
    }

    bf16x8 af[8], bfr[4];
#pragma unroll
    for (int i = 0; i < 8; i++)
      af[i] = *(const bf16x8*)&lsA[sk][quad][i * 16 + r16][0];
#pragma unroll
    for (int j = 0; j < 4; j++)
      bfr[j] = *(const bf16x8*)&lsB[sk][quad][w * 64 + j * 16 + r16][0];
#pragma unroll
    for (int j = 0; j < 4; j++)
#pragma unroll
      for (int i = 0; i < 8; i++)
        acc[i][j] = __builtin_amdgcn_mfma_f32_16x16x32_bf16(af[i], bfr[j],
                                                            acc[i][j], 0, 0, 0);
    sk = (sk + 1 == 3) ? 0 : sk + 1;
  }
#undef ISSUE_TILE

  // epilogue: C/D layout col=lane&15, row=quad*4+reg  [m89-verified]
#pragma unroll
  for (int j = 0; j < 4; j++) {
    int gn = n0 + w * 64 + j * 16 + r16;
    int cn = gn < N ? gn : 0;
    float p0, p1 = 0.f;
    if constexpr (EPI == 2) {
      p0 = scale[cn];
      p1 = shift[cn];
    } else {
      p0 = bias[cn];
    }
#pragma unroll
    for (int i = 0; i < 8; i++) {
#pragma unroll
      for (int t = 0; t < 4; t++) {
        int gm = m0 + i * 16 + quad * 4 + t;
        if (gm < M && gn < N) {
          float v = acc[i][j][t];
          if constexpr (EPI == 0) {
            v += p0;
            C[(size_t)gm * ldc + gn] = f2b(v);
          } else if constexpr (EPI == 1) {
            v += p0; v = v > 0.f ? v : 0.f;
            C[(size_t)gm * ldc + gn] = f2b(v);
          } else if constexpr (EPI == 2) {
            v = v * p0 + p1; v = v > 0.f ? v : 0.f;
            C[(size_t)gm * ldc + gn] = f2b(v);
          } else if constexpr (EPI == 3) {
            v += p0; v = v > 0.f ? v : 0.01f * v;
            C[(size_t)gm * ldc + gn] = f2b(v);
          } else {  // sigmoid -> fp32 network output
            v += p0;
            v = 1.f / (1.f + __expf(-v));
            ((float*)C)[(size_t)gm * ldc + gn] = v;
          }
        }
      }
    }
  }
}

// ---------------------------------------------------------------------------
extern "C" void kernel_launch(void* const* d_in, const int* in_sizes, int n_in,
                              void* d_out, int out_size, void* d_ws,
                              size_t ws_size, hipStream_t stream) {
  typedef const float* cf;
  cf x = (cf)d_in[0];
  const int* ei = (const int*)d_in[1];
  const int* srcI = ei;
  const int* dstI = ei + NE;
  cf w1a = (cf)d_in[2],  b1a = (cf)d_in[3];
  cf ga = (cf)d_in[4],   bea = (cf)d_in[5];
  cf mna = (cf)d_in[6],  vra = (cf)d_in[7];
  cf w2a = (cf)d_in[8],  b2a = (cf)d_in[9];
  cf w1b = (cf)d_in[10], b1b = (cf)d_in[11];
  cf gb = (cf)d_in[12],  beb = (cf)d_in[13];
  cf mnb = (cf)d_in[14], vrb = (cf)d_in[15];
  cf w2b = (cf)d_in[16], b2b = (cf)d_in[17];
  cf fc_w = (cf)d_in[18], fc_b = (cf)d_in[19];
  cf l1_w = (cf)d_in[20], l1_b = (cf)d_in[21];
  cf l2_w = (cf)d_in[22], l2_b = (cf)d_in[23];
  cf ow = (cf)d_in[24],   ob = (cf)d_in[25];
  float* outf = (float*)d_out;

  // ---- workspace carve-up ----------------------------------------------------
  char* ws = (char*)d_ws;
  size_t off = 0;
  auto carve = [&](size_t bytes) {
    void* p = ws + off;
    off += (bytes + 255) & ~(size_t)255;
    return p;
  };
  // persistent (~53 MB): transposed weights + h0 + folded BN params
  unsigned short* wt1ab = (unsigned short*)carve((size_t)DCAT * C_IN * 2);
  unsigned short* wt2a = (unsigned short*)carve((size_t)HID * HID * 2);
  unsigned short* wt2b = (unsigned short*)carve((size_t)HID * HID * 2);
  unsigned short* wtfc = (unsigned short*)carve((size_t)DFC * DCAT * 2);
  unsigned short* wtl1 = (unsigned short*)carve((size_t)DL1 * DFC * 2);
  unsigned short* wtl2 = (unsigned short*)carve((size_t)DFC * DL1 * 2);
  unsigned short* wtout = (unsigned short*)carve((size_t)OUTC * DFC * 2);
  float* scale_ab = (float*)carve(DCAT * 4);
  float* shift_ab = (float*)carve(DCAT * 4);
  unsigned short* h0 = (unsigned short*)carve((size_t)NN * C_IN * 2);

  // phase-1-only CSR arrays, OVERLAID with phase-2 activation buffers
  size_t off_overlay = off;
  int* deg = (int*)carve((size_t)NN * 4);
  int* offs = (int*)carve((size_t)(NN + 1) * 4);
  int* cursor = (int*)carve((size_t)NN * 4);
  int* bsum = (int*)carve(256 * 4);
  int* esrc = (int*)carve((size_t)NE * 4);

  // phase-2 activations from the overlay region start
  off = off_overlay;
  size_t rem = (ws_size > off + 4096) ? (ws_size - off - 4096) : 0;
  int mchunk = (int)(rem / ((DFC + DL1) * 2));
  if (mchunk > 15104) mchunk = 15104;
  mchunk &= ~127;
  if (mchunk < 128) mchunk = 128;
  unsigned short* bufA = (unsigned short*)carve((size_t)mchunk * DFC * 2);
  unsigned short* bufB = (unsigned short*)carve((size_t)mchunk * DL1 * 2);
  (void)in_sizes; (void)n_in; (void)out_size;

  // ---- phase 0: params + weight transposes ----------------------------------
  k_bnparams<<<2, 256, 0, stream>>>(ga, bea, mna, vra, b1a, scale_ab, shift_ab);
  k_bnparams<<<2, 256, 0, stream>>>(gb, beb, mnb, vrb, b1b, scale_ab + HID,
                                    shift_ab + HID);
  k_transpose<<<dim3(HID / 32, C_IN / 32), 256, 0, stream>>>(w1a, wt1ab, C_IN, HID);
  k_transpose<<<dim3(HID / 32, C_IN / 32), 256, 0, stream>>>(
      w1b, wt1ab + (size_t)HID * C_IN, C_IN, HID);
  k_transpose<<<dim3(HID / 32, HID / 32), 256, 0, stream>>>(w2a, wt2a, HID, HID);
  k_transpose<<<dim3(HID / 32, HID / 32), 256, 0, stream>>>(w2b, wt2b, HID, HID);
  k_transpose<<<dim3(DFC / 32, DCAT / 32), 256, 0, stream>>>(fc_w, wtfc, DCAT, DFC);
  k_transpose<<<dim3(DL1 / 32, DFC / 32), 256, 0, stream>>>(l1_w, wtl1, DFC, DL1);
  k_transpose<<<dim3(DFC / 32, DL1 / 32), 256, 0, stream>>>(l2_w, wtl2, DL1, DFC);
  k_transpose<<<dim3(OUTC / 32, DFC / 32), 256, 0, stream>>>(ow, wtout, DFC, OUTC);

  // ---- phase 1: CSR build + gather aggregation -------------------------------
  const int NB_NODE = (NN + 255) / 256;
  hipMemsetAsync(deg, 0, (size_t)NN * 4, stream);
  k_deg<<<(NE + 255) / 256, 256, 0, stream>>>(dstI, deg);
  k_scan1<<<NB_NODE, 256, 0, stream>>>(deg, offs, bsum);
  k_scan2<<<1, 256, 0, stream>>>(bsum, NB_NODE);
  k_scan3<<<NB_NODE, 256, 0, stream>>>(offs, bsum, cursor);
  k_bucket<<<(NE + 255) / 256, 256, 0, stream>>>(srcI, dstI, cursor, esrc);
  k_agg<<<(NN + 3) / 4, 256, 0, stream>>>((const float2*)x, offs, esrc,
                                          (unsigned int*)h0);

  // ---- phase 2: GEMM chain, M in adaptive chunks -----------------------------
  auto gemm = [&](int epi, const unsigned short* A, const unsigned short* Bt,
                  unsigned short* Cp, cf bias, const float* sc, const float* sh,
                  int M, int N, int K, int lda, int ldc) {
    dim3 g(((M + 127) / 128) * ((N + 255) / 256));
    switch (epi) {
      case 0: k_gemm<0><<<g, 256, 0, stream>>>(A, Bt, Cp, bias, sc, sh, M, N, K, lda, ldc); break;
      case 1: k_gemm<1><<<g, 256, 0, stream>>>(A, Bt, Cp, bias, sc, sh, M, N, K, lda, ldc); break;
      case 2: k_gemm<2><<<g, 256, 0, stream>>>(A, Bt, Cp, bias, sc, sh, M, N, K, lda, ldc); break;
      case 3: k_gemm<3><<<g, 256, 0, stream>>>(A, Bt, Cp, bias, sc, sh, M, N, K, lda, ldc); break;
      default: k_gemm<4><<<g, 256, 0, stream>>>(A, Bt, Cp, bias, sc, sh, M, N, K, lda, ldc); break;
    }
  };

  for (int m0 = 0; m0 < NN; m0 += mchunk) {
    const int M = (NN - m0 < mchunk) ? (NN - m0) : mchunk;
    const unsigned short* h0c = h0 + (size_t)m0 * C_IN;
    unsigned short* outc = (unsigned short*)(outf + (size_t)m0 * OUTC);
    // fused branch-1: t1 = BN+ReLU(h0 @ [w1a|w1b])  (M x 1024), bufA ld=1024
    gemm(2, h0c, wt1ab, bufA, nullptr, scale_ab, shift_ab, M, DCAT, C_IN, C_IN, DCAT);
    // branch-2a/b: xcat halves (bufB, ld=1024)
    gemm(1, bufA, wt2a, bufB, b2a, nullptr, nullptr, M, HID, HID, DCAT, DCAT);
    gemm(1, bufA + HID, wt2b, bufB + HID, b2b, nullptr, nullptr, M, HID, HID, DCAT, DCAT);
    // head: xcat(bufB,1024) -> hfc(bufA,2048) -> hl1(bufB,4096) -> hl2(bufA,2048) -> out(fp32)
    gemm(3, bufB, wtfc, bufA, fc_b, nullptr, nullptr, M, DFC, DCAT, DCAT, DFC);
    gemm(0, bufA, wtl1, bufB, l1_b, nullptr, nullptr, M, DL1, DFC, DFC, DL1);
    gemm(0, bufB, wtl2, bufA, l2_b, nullptr, nullptr, M, DFC, DL1, DL1, DFC);
    gemm(4, bufA, wtout, outc, ob, nullptr, nullptr, M, OUTC, DFC, DFC, OUTC);
  }
}

// Round 8
// 4964.681 us; speedup vs baseline: 1.1322x; 1.0316x over previous
//
#include <hip/hip_runtime.h>

// ---------------------------------------------------------------------------
// GCNConvNet: 2x GIN conv (shared aggregation) + dense head. fp32 I/O,
// bf16 MFMA internally (harness grants bf16 tolerance).
// Round 8: r7 analysis -> iteration wall ~4800cyc vs ~1050cyc MFMA = exposed
// cold-miss latency on A staging (A-tiles are read once per XCD -> L3/HBM).
// New k_gemm_g: B direct global->reg (L2-resident via XCD slice, reg dbuf);
// A via 4-stage glds pipeline, prefetch distance 3, tail-exact vmcnt drains.
// A/B test in one launch: l1 keeps r7 kernel (control, LDS 73728), l2 and
// all other layers use k_gemm_g (LDS 32768).
// ---------------------------------------------------------------------------

#define NN 60000
#define NE 960000
#define C_IN 128
#define HID 512
#define DCAT 1024
#define DFC 2048
#define DL1 4096
#define OUTC 64

typedef __bf16 bf16x8 __attribute__((ext_vector_type(8)));
typedef float floatx4 __attribute__((ext_vector_type(4)));

__device__ __forceinline__ unsigned short f2b(float f) {
  unsigned int u = __float_as_uint(f);
  unsigned int r = (u + 0x7fffu + ((u >> 16) & 1u)) >> 16;  // RNE, finite inputs
  return (unsigned short)r;
}

// async global->LDS, 16B per lane; LDS dest = wave-uniform base + lane*16
#define GLOAD_LDS16(g, l)                                                     \
  __builtin_amdgcn_global_load_lds(                                           \
      (__attribute__((address_space(1))) void*)(g),                           \
      (__attribute__((address_space(3))) void*)(l), 16, 0, 0)

// ---------------------------------------------------------------------------
__global__ void k_bnparams(const float* __restrict__ g,
                           const float* __restrict__ be,
                           const float* __restrict__ mn,
                           const float* __restrict__ vr,
                           const float* __restrict__ b1,
                           float* __restrict__ scale, float* __restrict__ shift) {
  int i = blockIdx.x * 256 + threadIdx.x;
  if (i < HID) {
    float s = g[i] * rsqrtf(vr[i] + 1e-5f);
    scale[i] = s;
    shift[i] = (b1[i] - mn[i]) * s + be[i];
  }
}

// fp32 [K,N] -> bf16 [N,K] transpose+downcast, 32x32 tiles
__global__ void k_transpose(const float* __restrict__ in,
                            unsigned short* __restrict__ out, int K, int N) {
  __shared__ float t[32][33];
  int n0 = blockIdx.x * 32, k0 = blockIdx.y * 32;
  int tx = threadIdx.x & 31, ty = threadIdx.x >> 5;  // 32 x 8
#pragma unroll
  for (int i = 0; i < 32; i += 8)
    t[ty + i][tx] = in[(size_t)(k0 + ty + i) * N + n0 + tx];
  __syncthreads();
#pragma unroll
  for (int i = 0; i < 32; i += 8)
    out[(size_t)(n0 + ty + i) * K + k0 + tx] = f2b(t[tx][ty + i]);
}

// ---------------------------------------------------------------------------
// CSR build: deg -> exclusive scan (3 kernels) -> bucket src ids -> gather.
__global__ void k_deg(const int* __restrict__ dst, int* __restrict__ deg) {
  int e = blockIdx.x * 256 + threadIdx.x;
  if (e < NE) atomicAdd(&deg[dst[e]], 1);
}

__global__ void k_scan1(const int* __restrict__ deg, int* __restrict__ offs,
                        int* __restrict__ bsum) {
  __shared__ int t[256];
  int i = blockIdx.x * 256 + threadIdx.x;
  int v = (i < NN) ? deg[i] : 0;
  t[threadIdx.x] = v;
  __syncthreads();
#pragma unroll
  for (int d = 1; d < 256; d <<= 1) {
    int add = (threadIdx.x >= d) ? t[threadIdx.x - d] : 0;
    __syncthreads();
    t[threadIdx.x] += add;
    __syncthreads();
  }
  if (i < NN) offs[i] = t[threadIdx.x] - v;
  if (threadIdx.x == 255) bsum[blockIdx.x] = t[255];
}

__global__ void k_scan2(int* __restrict__ bsum, int nb) {
  __shared__ int t[256];
  int v = (threadIdx.x < nb) ? bsum[threadIdx.x] : 0;
  t[threadIdx.x] = v;
  __syncthreads();
#pragma unroll
  for (int d = 1; d < 256; d <<= 1) {
    int add = (threadIdx.x >= d) ? t[threadIdx.x - d] : 0;
    __syncthreads();
    t[threadIdx.x] += add;
    __syncthreads();
  }
  if (threadIdx.x < nb) bsum[threadIdx.x] = t[threadIdx.x] - v;
}

__global__ void k_scan3(int* __restrict__ offs, const int* __restrict__ bsum,
                        int* __restrict__ cursor) {
  int i = blockIdx.x * 256 + threadIdx.x;
  if (i < NN) {
    int o = offs[i] + bsum[blockIdx.x];
    offs[i] = o;
    cursor[i] = o;
  }
  if (i == 0) offs[NN] = NE;
}

__global__ void k_bucket(const int* __restrict__ src, const int* __restrict__ dst,
                         int* __restrict__ cursor, int* __restrict__ esrc) {
  int e = blockIdx.x * 256 + threadIdx.x;
  if (e < NE) {
    int slot = atomicAdd(&cursor[dst[e]], 1);
    esrc[slot] = src[e];
  }
}

// one wave per node: h0[node] = bf16(x[node] + sum_j x[esrc[j]]), f32 accum
__global__ void k_agg(const float2* __restrict__ x2, const int* __restrict__ offs,
                      const int* __restrict__ esrc, unsigned int* __restrict__ h0u) {
  int node = blockIdx.x * 4 + (threadIdx.x >> 6);
  if (node >= NN) return;
  int lane = threadIdx.x & 63;
  int beg = offs[node], end = offs[node + 1];
  float2 acc = x2[(size_t)node * 64 + lane];
  for (int j = beg; j < end; j++) {
    int s = esrc[j];  // wave-uniform -> broadcast load
    float2 v = x2[(size_t)s * 64 + lane];
    acc.x += v.x;
    acc.y += v.y;
  }
  h0u[(size_t)node * 64 + lane] =
      (unsigned)f2b(acc.x) | ((unsigned)f2b(acc.y) << 16);
}

// ---------------------------------------------------------------------------
// shared epilogue: C/D layout col=lane&15, row=quad*4+reg  [m89-verified]
template <int EPI>
__device__ __forceinline__ void gemm_epilogue(
    floatx4 (&acc)[8][4], unsigned short* C, const float* bias,
    const float* scale, const float* shift, int M, int N, int ldc, int m0,
    int n0, int w, int quad, int r16) {
#pragma unroll
  for (int j = 0; j < 4; j++) {
    int gn = n0 + w * 64 + j * 16 + r16;
    int cn = gn < N ? gn : 0;
    float p0, p1 = 0.f;
    if constexpr (EPI == 2) {
      p0 = scale[cn];
      p1 = shift[cn];
    } else {
      p0 = bias[cn];
    }
#pragma unroll
    for (int i = 0; i < 8; i++) {
#pragma unroll
      for (int t = 0; t < 4; t++) {
        int gm = m0 + i * 16 + quad * 4 + t;
        if (gm < M && gn < N) {
          float v = acc[i][j][t];
          if constexpr (EPI == 0) {
            v += p0;
            C[(size_t)gm * ldc + gn] = f2b(v);
          } else if constexpr (EPI == 1) {
            v += p0; v = v > 0.f ? v : 0.f;
            C[(size_t)gm * ldc + gn] = f2b(v);
          } else if constexpr (EPI == 2) {
            v = v * p0 + p1; v = v > 0.f ? v : 0.f;
            C[(size_t)gm * ldc + gn] = f2b(v);
          } else if constexpr (EPI == 3) {
            v += p0; v = v > 0.f ? v : 0.01f * v;
            C[(size_t)gm * ldc + gn] = f2b(v);
          } else {  // sigmoid -> fp32 network output
            v += p0;
            v = 1.f / (1.f + __expf(-v));
            ((float*)C)[(size_t)gm * ldc + gn] = v;
          }
        }
      }
    }
  }
}

__device__ __forceinline__ void gemm_swizzle(int M, int N, int& m0, int& n0) {
  const int mt_total = (M + 127) >> 7, nt_total = (N + 255) >> 8;
  int mt, nt;
  if ((nt_total & 7) == 0) {
    const int ntpx = nt_total >> 3;
    const int x = blockIdx.x & 7;
    const int s = blockIdx.x >> 3;
    nt = x * ntpx + (s % ntpx);
    mt = s / ntpx;
  } else {
    const int GM = 8;
    const int full = (mt_total / GM) * GM;
    const int boundary = full * nt_total;
    int id = blockIdx.x;
    if (id < boundary) {
      int per_group = GM * nt_total;
      int g = id / per_group, r = id % per_group;
      mt = g * GM + r % GM;
      nt = r / GM;
    } else {
      int r = id - boundary, gm = mt_total - full;
      mt = full + r % gm;
      nt = r / gm;
    }
  }
  m0 = mt << 7;
  n0 = nt << 8;
}

// ---------------------------------------------------------------------------
// r7 control kernel: block 128x256, 3-stage A+B LDS pipeline, vmcnt(6).
template <int EPI>
__global__ __launch_bounds__(256, 2) void k_gemm(
    const unsigned short* __restrict__ A, const unsigned short* __restrict__ Bt,
    unsigned short* __restrict__ C, const float* __restrict__ bias,
    const float* __restrict__ scale, const float* __restrict__ shift,
    int M, int N, int K, int lda, int ldc) {
  __shared__ __align__(16) unsigned short lsA[3][4][128][8];  // 24 KB
  __shared__ __align__(16) unsigned short lsB[3][4][256][8];  // 48 KB

  const int tid = threadIdx.x;
  const int w = tid >> 6;
  const int lane = tid & 63;
  const int quad = lane >> 4;
  const int r16 = lane & 15;

  int m0, n0;
  gemm_swizzle(M, N, m0, n0);

  const int ra0 = min(m0 + lane, M - 1);
  const int ra1 = min(m0 + 64 + lane, M - 1);
  const unsigned short* pA0 = A + (size_t)ra0 * lda + w * 8;
  const unsigned short* pA1 = A + (size_t)ra1 * lda + w * 8;
  const unsigned short* pB[4];
#pragma unroll
  for (int seg = 0; seg < 4; seg++) {
    int rb = min(n0 + seg * 64 + lane, N - 1);
    pB[seg] = Bt + (size_t)rb * K + w * 8;
  }

  floatx4 acc[8][4];
#pragma unroll
  for (int i = 0; i < 8; i++)
#pragma unroll
    for (int j = 0; j < 4; j++) acc[i][j] = (floatx4){0.f, 0.f, 0.f, 0.f};

  const int niter = K >> 5;

#define ISSUE_TILE(st)                                                        \
  do {                                                                        \
    GLOAD_LDS16(pA0, &lsA[st][w][0][0]);                                      \
    GLOAD_LDS16(pA1, &lsA[st][w][64][0]);                                     \
    GLOAD_LDS16(pB[0], &lsB[st][w][0][0]);                                    \
    GLOAD_LDS16(pB[1], &lsB[st][w][64][0]);                                   \
    GLOAD_LDS16(pB[2], &lsB[st][w][128][0]);                                  \
    GLOAD_LDS16(pB[3], &lsB[st][w][192][0]);                                  \
    pA0 += 32; pA1 += 32;                                                     \
    pB[0] += 32; pB[1] += 32; pB[2] += 32; pB[3] += 32;                       \
  } while (0)

  ISSUE_TILE(0);
  if (niter > 1) ISSUE_TILE(1);

  int sk = 0;
  for (int t = 0; t < niter; t++) {
    if (t + 1 < niter) {
      asm volatile("s_waitcnt vmcnt(6)\n\ts_barrier" ::: "memory");
    } else {
      asm volatile("s_waitcnt vmcnt(0)\n\ts_barrier" ::: "memory");
    }
    if (t + 2 < niter) {
      int s2 = sk + 2;
      if (s2 >= 3) s2 -= 3;
      ISSUE_TILE(s2);
    }

    bf16x8 af[8], bfr[4];
#pragma unroll
    for (int i = 0; i < 8; i++)
      af[i] = *(const bf16x8*)&lsA[sk][quad][i * 16 + r16][0];
#pragma unroll
    for (int j = 0; j < 4; j++)
      bfr[j] = *(const bf16x8*)&lsB[sk][quad][w * 64 + j * 16 + r16][0];
#pragma unroll
    for (int j = 0; j < 4; j++)
#pragma unroll
      for (int i = 0; i < 8; i++)
        acc[i][j] = __builtin_amdgcn_mfma_f32_16x16x32_bf16(af[i], bfr[j],
                                                            acc[i][j], 0, 0, 0);
    sk = (sk + 1 == 3) ? 0 : sk + 1;
  }
#undef ISSUE_TILE

  gemm_epilogue<EPI>(acc, C, bias, scale, shift, M, N, ldc, m0, n0, w, quad, r16);
}

// ---------------------------------------------------------------------------
// NEW: B direct global->reg (L2-resident, reg dbuf); A via 4-stage glds
// pipeline with prefetch distance 3 and tail-exact partial drains.
// Per-iter issue order: [A glds t+3 (2 ops)] [B reg loads t+1 (4 ops)].
// At barrier(t), newer-than-A(t) outstanding = B(t):4 + A(t+1):2 + A(t+2):2
// -> vmcnt(8), degrading to 6/4 at the tail. B-load consumption is ordered
// by the compiler's own register-dependency waits.
template <int EPI>
__global__ __launch_bounds__(256, 2) void k_gemm_g(
    const unsigned short* __restrict__ A, const unsigned short* __restrict__ Bt,
    unsigned short* __restrict__ C, const float* __restrict__ bias,
    const float* __restrict__ scale, const float* __restrict__ shift,
    int M, int N, int K, int lda, int ldc) {
  __shared__ __align__(16) unsigned short lsA[4][4][128][8];  // 32 KB

  const int tid = threadIdx.x;
  const int w = tid >> 6;
  const int lane = tid & 63;
  const int quad = lane >> 4;
  const int r16 = lane & 15;

  int m0, n0;
  gemm_swizzle(M, N, m0, n0);

  const int ra0 = min(m0 + lane, M - 1);
  const int ra1 = min(m0 + 64 + lane, M - 1);
  const unsigned short* pA0 = A + (size_t)ra0 * lda + w * 8;
  const unsigned short* pA1 = A + (size_t)ra1 * lda + w * 8;
  // B fragment pointers: lane loads B[n0+w*64+j*16+r16][k0+quad*8 .. +8]
  const unsigned short* pB[4];
#pragma unroll
  for (int j = 0; j < 4; j++) {
    int rb = min(n0 + w * 64 + j * 16 + r16, N - 1);
    pB[j] = Bt + (size_t)rb * K + quad * 8;
  }

  floatx4 acc[8][4];
#pragma unroll
  for (int i = 0; i < 8; i++)
#pragma unroll
    for (int j = 0; j < 4; j++) acc[i][j] = (floatx4){0.f, 0.f, 0.f, 0.f};

  const int niter = K >> 5;

#define ISSUE_A(st)                                                           \
  do {                                                                        \
    GLOAD_LDS16(pA0, &lsA[st][w][0][0]);                                      \
    GLOAD_LDS16(pA1, &lsA[st][w][64][0]);                                     \
    pA0 += 32; pA1 += 32;                                                     \
  } while (0)

  ISSUE_A(0);
  if (niter > 1) ISSUE_A(1);
  if (niter > 2) ISSUE_A(2);
  bf16x8 bcur[4], bnxt[4];
#pragma unroll
  for (int j = 0; j < 4; j++) {
    bcur[j] = *(const bf16x8*)pB[j];
    pB[j] += 32;
  }

  int st = 0;
  for (int t = 0; t < niter; t++) {
    if (t + 2 < niter) {
      asm volatile("s_waitcnt vmcnt(8)\n\ts_barrier" ::: "memory");
    } else if (t + 1 < niter) {
      asm volatile("s_waitcnt vmcnt(6)\n\ts_barrier" ::: "memory");
    } else {
      asm volatile("s_waitcnt vmcnt(4)\n\ts_barrier" ::: "memory");
    }
    if (t + 3 < niter) {
      int s3 = st + 3;
      if (s3 >= 4) s3 -= 4;
      ISSUE_A(s3);
    }
    if (t + 1 < niter) {
#pragma unroll
      for (int j = 0; j < 4; j++) {
        bnxt[j] = *(const bf16x8*)pB[j];
        pB[j] += 32;
      }
    }

    bf16x8 af[8];
#pragma unroll
    for (int i = 0; i < 8; i++)
      af[i] = *(const bf16x8*)&lsA[st][quad][i * 16 + r16][0];
#pragma unroll
    for (int j = 0; j < 4; j++)
#pragma unroll
      for (int i = 0; i < 8; i++)
        acc[i][j] = __builtin_amdgcn_mfma_f32_16x16x32_bf16(af[i], bcur[j],
                                                            acc[i][j], 0, 0, 0);
#pragma unroll
    for (int j = 0; j < 4; j++) bcur[j] = bnxt[j];
    st = (st + 1) & 3;
  }
#undef ISSUE_A

  gemm_epilogue<EPI>(acc, C, bias, scale, shift, M, N, ldc, m0, n0, w, quad, r16);
}

// ---------------------------------------------------------------------------
extern "C" void kernel_launch(void* const* d_in, const int* in_sizes, int n_in,
                              void* d_out, int out_size, void* d_ws,
                              size_t ws_size, hipStream_t stream) {
  typedef const float* cf;
  cf x = (cf)d_in[0];
  const int* ei = (const int*)d_in[1];
  const int* srcI = ei;
  const int* dstI = ei + NE;
  cf w1a = (cf)d_in[2],  b1a = (cf)d_in[3];
  cf ga = (cf)d_in[4],   bea = (cf)d_in[5];
  cf mna = (cf)d_in[6],  vra = (cf)d_in[7];
  cf w2a = (cf)d_in[8],  b2a = (cf)d_in[9];
  cf w1b = (cf)d_in[10], b1b = (cf)d_in[11];
  cf gb = (cf)d_in[12],  beb = (cf)d_in[13];
  cf mnb = (cf)d_in[14], vrb = (cf)d_in[15];
  cf w2b = (cf)d_in[16], b2b = (cf)d_in[17];
  cf fc_w = (cf)d_in[18], fc_b = (cf)d_in[19];
  cf l1_w = (cf)d_in[20], l1_b = (cf)d_in[21];
  cf l2_w = (cf)d_in[22], l2_b = (cf)d_in[23];
  cf ow = (cf)d_in[24],   ob = (cf)d_in[25];
  float* outf = (float*)d_out;

  // ---- workspace carve-up ----------------------------------------------------
  char* ws = (char*)d_ws;
  size_t off = 0;
  auto carve = [&](size_t bytes) {
    void* p = ws + off;
    off += (bytes + 255) & ~(size_t)255;
    return p;
  };
  unsigned short* wt1ab = (unsigned short*)carve((size_t)DCAT * C_IN * 2);
  unsigned short* wt2a = (unsigned short*)carve((size_t)HID * HID * 2);
  unsigned short* wt2b = (unsigned short*)carve((size_t)HID * HID * 2);
  unsigned short* wtfc = (unsigned short*)carve((size_t)DFC * DCAT * 2);
  unsigned short* wtl1 = (unsigned short*)carve((size_t)DL1 * DFC * 2);
  unsigned short* wtl2 = (unsigned short*)carve((size_t)DFC * DL1 * 2);
  unsigned short* wtout = (unsigned short*)carve((size_t)OUTC * DFC * 2);
  float* scale_ab = (float*)carve(DCAT * 4);
  float* shift_ab = (float*)carve(DCAT * 4);
  unsigned short* h0 = (unsigned short*)carve((size_t)NN * C_IN * 2);

  // phase-1-only CSR arrays, OVERLAID with phase-2 activation buffers
  size_t off_overlay = off;
  int* deg = (int*)carve((size_t)NN * 4);
  int* offs = (int*)carve((size_t)(NN + 1) * 4);
  int* cursor = (int*)carve((size_t)NN * 4);
  int* bsum = (int*)carve(256 * 4);
  int* esrc = (int*)carve((size_t)NE * 4);

  off = off_overlay;
  size_t rem = (ws_size > off + 4096) ? (ws_size - off - 4096) : 0;
  int mchunk = (int)(rem / ((DFC + DL1) * 2));
  if (mchunk > 15104) mchunk = 15104;
  mchunk &= ~127;
  if (mchunk < 128) mchunk = 128;
  unsigned short* bufA = (unsigned short*)carve((size_t)mchunk * DFC * 2);
  unsigned short* bufB = (unsigned short*)carve((size_t)mchunk * DL1 * 2);
  (void)in_sizes; (void)n_in; (void)out_size;

  // ---- phase 0: params + weight transposes ----------------------------------
  k_bnparams<<<2, 256, 0, stream>>>(ga, bea, mna, vra, b1a, scale_ab, shift_ab);
  k_bnparams<<<2, 256, 0, stream>>>(gb, beb, mnb, vrb, b1b, scale_ab + HID,
                                    shift_ab + HID);
  k_transpose<<<dim3(HID / 32, C_IN / 32), 256, 0, stream>>>(w1a, wt1ab, C_IN, HID);
  k_transpose<<<dim3(HID / 32, C_IN / 32), 256, 0, stream>>>(
      w1b, wt1ab + (size_t)HID * C_IN, C_IN, HID);
  k_transpose<<<dim3(HID / 32, HID / 32), 256, 0, stream>>>(w2a, wt2a, HID, HID);
  k_transpose<<<dim3(HID / 32, HID / 32), 256, 0, stream>>>(w2b, wt2b, HID, HID);
  k_transpose<<<dim3(DFC / 32, DCAT / 32), 256, 0, stream>>>(fc_w, wtfc, DCAT, DFC);
  k_transpose<<<dim3(DL1 / 32, DFC / 32), 256, 0, stream>>>(l1_w, wtl1, DFC, DL1);
  k_transpose<<<dim3(DFC / 32, DL1 / 32), 256, 0, stream>>>(l2_w, wtl2, DL1, DFC);
  k_transpose<<<dim3(OUTC / 32, DFC / 32), 256, 0, stream>>>(ow, wtout, DFC, OUTC);

  // ---- phase 1: CSR build + gather aggregation -------------------------------
  const int NB_NODE = (NN + 255) / 256;
  hipMemsetAsync(deg, 0, (size_t)NN * 4, stream);
  k_deg<<<(NE + 255) / 256, 256, 0, stream>>>(dstI, deg);
  k_scan1<<<NB_NODE, 256, 0, stream>>>(deg, offs, bsum);
  k_scan2<<<1, 256, 0, stream>>>(bsum, NB_NODE);
  k_scan3<<<NB_NODE, 256, 0, stream>>>(offs, bsum, cursor);
  k_bucket<<<(NE + 255) / 256, 256, 0, stream>>>(srcI, dstI, cursor, esrc);
  k_agg<<<(NN + 3) / 4, 256, 0, stream>>>((const float2*)x, offs, esrc,
                                          (unsigned int*)h0);

  // ---- phase 2: GEMM chain ---------------------------------------------------
  // variant: 0 = r7 control (A+B LDS 3-stage), 1 = G (B-direct, A 4-stage)
  auto gemm = [&](int var, int epi, const unsigned short* A,
                  const unsigned short* Bt, unsigned short* Cp, cf bias,
                  const float* sc, const float* sh, int M, int N, int K,
                  int lda, int ldc) {
    dim3 g(((M + 127) / 128) * ((N + 255) / 256));
    if (var == 0) {
      switch (epi) {
        case 0: k_gemm<0><<<g, 256, 0, stream>>>(A, Bt, Cp, bias, sc, sh, M, N, K, lda, ldc); break;
        case 1: k_gemm<1><<<g, 256, 0, stream>>>(A, Bt, Cp, bias, sc, sh, M, N, K, lda, ldc); break;
        case 2: k_gemm<2><<<g, 256, 0, stream>>>(A, Bt, Cp, bias, sc, sh, M, N, K, lda, ldc); break;
        case 3: k_gemm<3><<<g, 256, 0, stream>>>(A, Bt, Cp, bias, sc, sh, M, N, K, lda, ldc); break;
        default: k_gemm<4><<<g, 256, 0, stream>>>(A, Bt, Cp, bias, sc, sh, M, N, K, lda, ldc); break;
      }
    } else {
      switch (epi) {
        case 0: k_gemm_g<0><<<g, 256, 0, stream>>>(A, Bt, Cp, bias, sc, sh, M, N, K, lda, ldc); break;
        case 1: k_gemm_g<1><<<g, 256, 0, stream>>>(A, Bt, Cp, bias, sc, sh, M, N, K, lda, ldc); break;
        case 2: k_gemm_g<2><<<g, 256, 0, stream>>>(A, Bt, Cp, bias, sc, sh, M, N, K, lda, ldc); break;
        case 3: k_gemm_g<3><<<g, 256, 0, stream>>>(A, Bt, Cp, bias, sc, sh, M, N, K, lda, ldc); break;
        default: k_gemm_g<4><<<g, 256, 0, stream>>>(A, Bt, Cp, bias, sc, sh, M, N, K, lda, ldc); break;
      }
    }
  };

  for (int m0 = 0; m0 < NN; m0 += mchunk) {
    const int M = (NN - m0 < mchunk) ? (NN - m0) : mchunk;
    const unsigned short* h0c = h0 + (size_t)m0 * C_IN;
    unsigned short* outc = (unsigned short*)(outf + (size_t)m0 * OUTC);
    // fused branch-1: t1 = BN+ReLU(h0 @ [w1a|w1b])  (M x 1024), bufA ld=1024
    gemm(1, 2, h0c, wt1ab, bufA, nullptr, scale_ab, shift_ab, M, DCAT, C_IN, C_IN, DCAT);
    // branch-2a/b: xcat halves (bufB, ld=1024)
    gemm(1, 1, bufA, wt2a, bufB, b2a, nullptr, nullptr, M, HID, HID, DCAT, DCAT);
    gemm(1, 1, bufA + HID, wt2b, bufB + HID, b2b, nullptr, nullptr, M, HID, HID, DCAT, DCAT);
    // head: xcat(bufB,1024) -> hfc(bufA,2048) -> hl1(bufB,4096) -> hl2(bufA,2048) -> out
    gemm(1, 3, bufB, wtfc, bufA, fc_b, nullptr, nullptr, M, DFC, DCAT, DCAT, DFC);
    gemm(0, 0, bufA, wtl1, bufB, l1_b, nullptr, nullptr, M, DL1, DFC, DFC, DL1);   // l1 = r7 CONTROL
    gemm(1, 0, bufB, wtl2, bufA, l2_b, nullptr, nullptr, M, DFC, DL1, DL1, DFC);   // l2 = G
    gemm(1, 4, bufA, wtout, outc, ob, nullptr, nullptr, M, OUTC, DFC, DFC, OUTC);
  }
}